// Round 17
// baseline (85.478 us; speedup 1.0000x reference)
//
#include <hip/hip_runtime.h>
#include <stddef.h>

// Additive attention: out = softmax_k(mask(sum_h wv_h * tanh(qW_h + kW_h))) @ V
// tanh(q+k) = 1 - 2/(1 + e^{2q} e^{2k})  -> precompute Eq=e^{2q}, Ek=e^{2k};
// score = W0 + sum_h wv2_h * rcp(1 + Eq_h*Ek_h); |score| <= W1 = sum|wv| ->
// p = exp2((s-W1)*L2E) in (0,1], no max pass; normalize at the end.
//
// Round-17 = Round-16 with the q0gBase compile error fixed (helper inlined).
// q-tile 32 (units = 4*as ~ 544 <= 768 blocks -> single queue round, no
// 2-round tail) + ek staged once per 32 q + init merged into proj launch.

__device__ __forceinline__ float fast_rcp(float x)  { return __builtin_amdgcn_rcpf(x); }
__device__ __forceinline__ float fast_exp2(float x) { return __builtin_amdgcn_exp2f(x); }

#define C2F 2.88539008177792681f   // 2*log2(e)
#define L2E 1.44269504088896340f   // log2(e)

#if __has_builtin(__builtin_amdgcn_global_load_lds)
#define HAS_GLL 1
__device__ __forceinline__ void gload_lds16(const void* gsrc, void* ldst) {
  __builtin_amdgcn_global_load_lds(
      (const __attribute__((address_space(1))) unsigned int*)gsrc,
      (__attribute__((address_space(3))) unsigned int*)ldst, 16, 0, 0);
}
#else
#define HAS_GLL 0
#endif

// meta ints: [0]=cnt_score [1]=n_score ; [32..48]=pre_sc (prefix ceil(vl/128))
#define M_CNTS 0
#define M_NS   1
#define M_PSC  32

// ---------------------------------------------------------------------------
// Projection body: P = in[64 rows x 256] @ W[256 x 64], E = exp2(C2F*P).
// MODE 0: row-major [row][64]           (fallback queries)
// MODE 1: legacy EkT [b][kt][h][128]    (fallback keys)
// MODE 2: packed Ek  [b][kt][hp][k][2]  (main keys)
// MODE 3: packed EqW [b][q][hp]{eq0,eq1,-2wv0,-2wv1} float4 (main queries)
// ---------------------------------------------------------------------------
template<int MODE>
__device__ __forceinline__
void proj_body(const float* __restrict__ inb, const float* __restrict__ W,
               float* __restrict__ out, const float* __restrict__ wv,
               int b, int r0, int rowsPerB, int t)
{
  __shared__ float4 Wlds[256 * 16];   // [d][h-quad]
  __shared__ float  klds[64 * 36];

  const float4* W4 = (const float4*)W;
#if HAS_GLL
  {
    float4* wdst = Wlds + (t & ~63);          // wave-uniform base
    #pragma unroll
    for (int i = 0; i < 16; ++i)
      gload_lds16(W4 + t + 256 * i, wdst + 256 * i);
  }
#else
  #pragma unroll
  for (int i = 0; i < 16; ++i) Wlds[t + 256 * i] = W4[t + 256 * i];
#endif

  const int j = t >> 4;
  const int g = t & 15;

  float acc[4][4];
  #pragma unroll
  for (int m = 0; m < 4; ++m)
    acc[m][0] = acc[m][1] = acc[m][2] = acc[m][3] = 0.f;

  for (int dc = 0; dc < 8; ++dc) {
    {
      const int row = t >> 2, cs = (t & 3) * 8;
      const float* s = inb + row * 256 + dc * 32 + cs;
      float4 a0 = *(const float4*)s;
      float4 a1 = *(const float4*)(s + 4);
      float* dst = &klds[row * 36 + cs];
      *(float4*)dst       = a0;
      *(float4*)(dst + 4) = a1;
    }
    __syncthreads();
    #pragma unroll
    for (int d = 0; d < 32; ++d) {
      float4 w4 = Wlds[(dc * 32 + d) * 16 + j];
      #pragma unroll
      for (int m = 0; m < 4; ++m) {
        float kv = klds[(g + 16 * m) * 36 + d];
        acc[m][0] = fmaf(kv, w4.x, acc[m][0]);
        acc[m][1] = fmaf(kv, w4.y, acc[m][1]);
        acc[m][2] = fmaf(kv, w4.z, acc[m][2]);
        acc[m][3] = fmaf(kv, w4.w, acc[m][3]);
      }
    }
    __syncthreads();
  }

  if constexpr (MODE == 1) {
    #pragma unroll
    for (int m = 0; m < 4; ++m) {
      int k = r0 + g + 16 * m;
      size_t base = ((size_t)(b * 16 + (k >> 7)) * 64) * 128 + (k & 127);
      #pragma unroll
      for (int i = 0; i < 4; ++i)
        out[base + (size_t)(4 * j + i) * 128] = fast_exp2(C2F * acc[m][i]);
    }
  } else if constexpr (MODE == 2) {
    // packed: idx = tile*8192 + hp*256 + k_in*2 + hl, hp = h>>1
    #pragma unroll
    for (int m = 0; m < 4; ++m) {
      int k = r0 + g + 16 * m;
      size_t base = (size_t)(b * 16 + (k >> 7)) * 8192 + (size_t)(k & 127) * 2;
      float e0 = fast_exp2(C2F * acc[m][0]);
      float e1 = fast_exp2(C2F * acc[m][1]);
      float e2 = fast_exp2(C2F * acc[m][2]);
      float e3 = fast_exp2(C2F * acc[m][3]);
      *(float2*)&out[base + (size_t)(2 * j) * 256]     = make_float2(e0, e1);
      *(float2*)&out[base + (size_t)(2 * j + 1) * 256] = make_float2(e2, e3);
    }
  } else if constexpr (MODE == 3) {
    // EqW float4 [b*128+row][32hp]: {eq(2hp), eq(2hp+1), -2wv(2hp), -2wv(2hp+1)}
    float4 wq = ((const float4*)wv)[j];   // epilogue-only load
    #pragma unroll
    for (int m = 0; m < 4; ++m) {
      int row = r0 + g + 16 * m;
      float e0 = fast_exp2(C2F * acc[m][0]);
      float e1 = fast_exp2(C2F * acc[m][1]);
      float e2 = fast_exp2(C2F * acc[m][2]);
      float e3 = fast_exp2(C2F * acc[m][3]);
      float4* dst = (float4*)out + ((size_t)(b * 128 + row)) * 32;
      dst[2 * j]     = make_float4(e0, e1, -2.f * wq.x, -2.f * wq.y);
      dst[2 * j + 1] = make_float4(e2, e3, -2.f * wq.z, -2.f * wq.w);
    }
  } else {
    #pragma unroll
    for (int m = 0; m < 4; ++m) {
      int row = r0 + g + 16 * m;
      float4 o;
      o.x = fast_exp2(C2F * acc[m][0]);
      o.y = fast_exp2(C2F * acc[m][1]);
      o.z = fast_exp2(C2F * acc[m][2]);
      o.w = fast_exp2(C2F * acc[m][3]);
      *(float4*)&out[((size_t)b * rowsPerB + row) * 64 + 4 * j] = o;
    }
  }
}

// Merged q+k projection + init: blocks 0..511 keys (early-exit),
// 512..543 queries, 544 = meta init (single block).
__global__ __launch_bounds__(256)
void proj_qk_kernel(const float* __restrict__ queries, const float* __restrict__ keys,
                    const float* __restrict__ Wq, const float* __restrict__ Wk,
                    float* __restrict__ EqW, float* __restrict__ EkP,
                    const float* __restrict__ wv, const int* __restrict__ vlens,
                    int* __restrict__ meta)
{
  const int blk = blockIdx.x;
  if (blk == 544) {
    if (threadIdx.x == 0) {
      int as = 0;
      meta[M_PSC] = 0;
      for (int b = 0; b < 16; ++b) {
        as += (vlens[b] + 127) >> 7;
        meta[M_PSC + 1 + b] = as;
      }
      meta[M_NS]   = as * 4;     // 4 q-tiles (32 q) per active (b,kt)
      meta[M_CNTS] = 0;
    }
    return;
  }
  if (blk >= 512) {
    const int idx = blk - 512;
    const int b = idx & 15, rt = idx >> 4, r0 = rt * 64;
    proj_body<3>(queries + ((size_t)b * 128 + r0) * 256, Wq, EqW, wv, b, r0, 128,
                 threadIdx.x);
  } else {
    const int b = blk & 15, rt = blk >> 4, r0 = rt * 64;
    if (r0 >= vlens[b]) return;
    proj_body<2>(keys + ((size_t)b * 2048 + r0) * 256, Wk, EkP, wv, b, r0, 2048,
                 threadIdx.x);
  }
}

// Fallback projections (legacy layouts)
template<int MODE, bool CHECK>
__global__ __launch_bounds__(256)
void proj_kernel(const float* __restrict__ in, const float* __restrict__ W,
                 float* __restrict__ out, const int* __restrict__ vlens,
                 int rowsPerB)
{
  const int t  = threadIdx.x;
  const int b  = blockIdx.x & 15;
  const int rt = blockIdx.x >> 4;
  const int r0 = rt * 64;
  if constexpr (CHECK) {
    if (r0 >= vlens[b]) return;
  }
  proj_body<MODE>(in + ((size_t)b * rowsPerB + r0) * 256, W, out,
                  (const float*)nullptr, b, r0, rowsPerB, t);
}

// ---------------------------------------------------------------------------
// Persistent fused scores + exp + PV. 512 thr = 8 waves; wave owns 4 q,
// 32-q units: u -> w = u>>2 (b,kt via prefix), qq = u&3.
// Score loop: 1 vector ds_read_b128 (ek) + 4 broadcast b128 (eqw) per hp.
// PV: 4-way k-split, acc[32], 8-deep V batches; 3-zone LDS reduction.
// ---------------------------------------------------------------------------
__global__ __launch_bounds__(512, 6)
void scorepv_kernel(const float* __restrict__ EqW, const float* __restrict__ EkP,
                    const float* __restrict__ values, const int* __restrict__ vlens,
                    const float* __restrict__ wv,
                    float* __restrict__ partial, float* __restrict__ tsum,
                    int* __restrict__ meta)
{
  __shared__ float ek_lds[8192];       // 32KB packed ek [hp][k][2]; red 0/1 later
  __shared__ float p_lds[128 * 36];    // 18KB: eqw (16KB) during score,
                                       //       p [128k][36pad] during PV, red 2
  __shared__ int sh_u, sh_pre[17];

  const int t = threadIdx.x;
  if (t < 17) sh_pre[t] = meta[M_PSC + t];
  const int nunits = meta[M_NS];

  // W1 = sum|wv|, W0 = sum wv (once; outside hot loop)
  float W1 = 0.f, w0 = 0.f;
  #pragma unroll
  for (int u = 0; u < 16; ++u) {
    float4 v = ((const float4*)wv)[u];
    w0 += v.x + v.y + v.z + v.w;
    W1 += fabsf(v.x) + fabsf(v.y) + fabsf(v.z) + fabsf(v.w);
  }

  const int wave_u = __builtin_amdgcn_readfirstlane(t >> 6);  // 0..7 uniform
  const int lane   = t & 63;
  const int kp     = lane * 2;
  const int q0l    = wave_u * 4;       // wave's 4 exclusive q rows

  for (;;) {
    __syncthreads();                   // prev unit's red/p readers done
    if (t == 0) sh_u = atomicAdd(&meta[M_CNTS], 1);
    __syncthreads();
    const int u = sh_u;
    if (u >= nunits) break;

    const int w  = u >> 2;
    const int qq = u & 3;              // 32-q tile
    int b = 0;
    while (w >= sh_pre[1 + b]) ++b;
    const int kt = w - sh_pre[b];
    const int vl = vlens[b];

    // stage ek (32KB) + eqw (16KB, 32q x 32hp float4), lane-contiguous
    {
      const float4* src  = (const float4*)(EkP + (size_t)(b * 16 + kt) * 8192);
      const float4* qsrc = (const float4*)EqW + ((size_t)(b * 128 + qq * 32)) * 32;
#if HAS_GLL
      float4* dstw = (float4*)ek_lds + (t & ~63);     // wave-uniform base
      #pragma unroll
      for (int i = 0; i < 4; ++i)
        gload_lds16(src + t + 512 * i, dstw + 512 * i);
      float4* pdstw = (float4*)p_lds + (t & ~63);
      gload_lds16(qsrc + t,       pdstw);
      gload_lds16(qsrc + t + 512, pdstw + 512);
#else
      float4* dst = (float4*)ek_lds;
      #pragma unroll
      for (int i = 0; i < 4; ++i) dst[t + 512 * i] = src[t + 512 * i];
      ((float4*)p_lds)[t]       = qsrc[t];
      ((float4*)p_lds)[t + 512] = qsrc[t + 512];
#endif
    }
    __syncthreads();                   // staging complete

    float s[4][2];
    #pragma unroll
    for (int q = 0; q < 4; ++q) { s[q][0] = w0; s[q][1] = w0; }

    const float4* ek4 = (const float4*)ek_lds;
    const float4* eqw = (const float4*)p_lds;
    #pragma unroll 4
    for (int hp = 0; hp < 32; ++hp) {
      float4 e = ek4[hp * 64 + lane];          // (k,h0)(k,h1)(k+1,h0)(k+1,h1)
      #pragma unroll
      for (int q = 0; q < 4; ++q) {
        float4 ew = eqw[(q0l + q) * 32 + hp];  // {eq0,eq1,wa,wb} broadcast
        { float x0 = fmaf(ew.x, e.x, 1.f), x1 = fmaf(ew.y, e.y, 1.f);
          float y = fast_rcp(x0 * x1);
          float a = ew.w * x0; a = fmaf(ew.z, x1, a);
          s[q][0] = fmaf(a, y, s[q][0]); }
        { float x0 = fmaf(ew.x, e.z, 1.f), x1 = fmaf(ew.y, e.w, 1.f);
          float y = fast_rcp(x0 * x1);
          float a = ew.w * x0; a = fmaf(ew.z, x1, a);
          s[q][1] = fmaf(a, y, s[q][1]); }
      }
    }

    // p = exp2((s - W1)*L2E) in (0,1]; masked -> 0 (select, garbage-safe)
    const int kbase = kt * 128 + kp;
    float p[4][2];
    #pragma unroll
    for (int q = 0; q < 4; ++q) {
      p[q][0] = (kbase     < vl) ? fast_exp2((s[q][0] - W1) * L2E) : 0.f;
      p[q][1] = (kbase + 1 < vl) ? fast_exp2((s[q][1] - W1) * L2E) : 0.f;
    }

    // per-tile row sums (wave owns its q rows exclusively)
    const int q0g = qq * 32 + q0l;
    #pragma unroll
    for (int q = 0; q < 4; ++q) {
      float e = p[q][0] + p[q][1];
      #pragma unroll
      for (int m = 1; m < 64; m <<= 1) e += __shfl_xor(e, m, 64);
      if (lane == 0) tsum[(size_t)(b * 16 + kt) * 128 + q0g + q] = e;
    }

    __syncthreads();                   // all eqw reads done before p overlay
    *(float4*)&p_lds[kp * 36 + q0l]       = make_float4(p[0][0], p[1][0], p[2][0], p[3][0]);
    *(float4*)&p_lds[(kp + 1) * 36 + q0l] = make_float4(p[0][1], p[1][1], p[2][1], p[3][1]);
    __syncthreads();                   // p visible

    // PV: thread (kg 0..3, v); kg owns 32 k; 8-deep V-load batches;
    // p via broadcast ds_read_b128 (same-address: conflict-free)
    const int kg = t >> 7, v = t & 127;
    const int kloc = min(128, vl - kt * 128);
    const int k0 = kg * 32, k1 = min(k0 + 32, kloc);
    const int len = (k1 > k0) ? (k1 - k0) : 0;   // clamp (k1 may be < k0)
    const int nfull = len & ~7;
    const float* vb = values + ((size_t)(b * 2048 + kt * 128)) * 128 + v;
    float acc[32];
    #pragma unroll
    for (int i = 0; i < 32; ++i) acc[i] = 0.f;

    for (int kb = k0; kb < k0 + nfull; kb += 8) {
      float vv[8];
      #pragma unroll
      for (int j = 0; j < 8; ++j) vv[j] = vb[(size_t)(kb + j) * 128];
      #pragma unroll
      for (int j = 0; j < 8; ++j) {
        const float4* pr = (const float4*)&p_lds[(kb + j) * 36];
        float vx = vv[j];
        #pragma unroll
        for (int qg = 0; qg < 8; ++qg) {
          float4 pq = pr[qg];
          acc[4*qg+0] = fmaf(pq.x, vx, acc[4*qg+0]);
          acc[4*qg+1] = fmaf(pq.y, vx, acc[4*qg+1]);
          acc[4*qg+2] = fmaf(pq.z, vx, acc[4*qg+2]);
          acc[4*qg+3] = fmaf(pq.w, vx, acc[4*qg+3]);
        }
      }
    }
    for (int k = k0 + nfull; k < k1; ++k) {      // remainder (partial tiles)
      float vx = vb[(size_t)k * 128];
      const float* pr = &p_lds[k * 36];
      #pragma unroll
      for (int q = 0; q < 32; ++q) acc[q] = fmaf(pr[q], vx, acc[q]);
    }

    // 3-zone reduction over kg: kg1 -> ek[0..4095], kg2 -> ek[4096..8191],
    // kg3 -> p region (all reads of ek/p completed before this barrier)
    __syncthreads();
    if (kg == 1) {
      #pragma unroll
      for (int q = 0; q < 32; ++q) ek_lds[q * 128 + v] = acc[q];
    } else if (kg == 2) {
      #pragma unroll
      for (int q = 0; q < 32; ++q) ek_lds[4096 + q * 128 + v] = acc[q];
    } else if (kg == 3) {
      #pragma unroll
      for (int q = 0; q < 32; ++q) p_lds[q * 128 + v] = acc[q];
    }
    __syncthreads();
    if (kg == 0) {
      #pragma unroll
      for (int q = 0; q < 32; ++q) {
        float tot = acc[q] + ek_lds[q * 128 + v] + ek_lds[4096 + q * 128 + v]
                  + p_lds[q * 128 + v];
        partial[(((size_t)(b * 128 + qq * 32 + q)) * 16 + kt) * 128 + v] = tot;
      }
    }
  }
}

// ---------------------------------------------------------------------------
// Reduce: out[b][q][v] = sum_kt partial / sum_kt tsum. Block = (b, 2-q), 256 thr.
// ---------------------------------------------------------------------------
__global__ __launch_bounds__(256)
void reduce_kernel(const float* __restrict__ partial, const float* __restrict__ tsum,
                   const int* __restrict__ vlens, float* __restrict__ out)
{
  const int blk = blockIdx.x;          // b*64 + qp
  const int b   = blk >> 6;
  const int q   = (blk & 63) * 2 + (threadIdx.x >> 7);
  const int v   = threadIdx.x & 127;
  const int ntk = (vlens[b] + 127) >> 7;

  float tot = 0.f;
  for (int i = 0; i < ntk; ++i)
    tot += tsum[(size_t)(b * 16 + i) * 128 + q];

  float acc = 0.f;
  const float* pp = partial + ((size_t)(b * 128 + q)) * 16 * 128 + v;
  for (int i = 0; i < ntk; ++i)
    acc += pp[(size_t)i * 128];

  out[((size_t)(b * 128 + q)) * 128 + v] = acc / tot;
}

// ---------------------------------------------------------------------------
// Fallback fused kernel (round-1, known-correct) for small ws_size.
// ---------------------------------------------------------------------------
__global__ __launch_bounds__(256)
void attn_kernel(const float* __restrict__ Eq, const float* __restrict__ EkT,
                 const float* __restrict__ values, const int* __restrict__ vlens,
                 const float* __restrict__ wv, float* __restrict__ out)
{
  const int t    = threadIdx.x;
  const int b    = blockIdx.x & 15;
  const int qt   = blockIdx.x >> 4;
  const int wave = t >> 6;
  const int lane = t & 63;

  __shared__ float4 sc4[512 * 4];
  __shared__ float  pvp[128 * 5];
  __shared__ float  linvs[4];

  const int vl = vlens[b];

  float eqv[64], wv2[64];
  float w0 = 0.f;
  {
    const float4* eq4 = (const float4*)(Eq + (size_t)(b * 128 + qt * 4 + wave) * 64);
    const float4* wv4 = (const float4*)wv;
    #pragma unroll
    for (int u = 0; u < 16; ++u) {
      float4 e = eq4[u], v = wv4[u];
      eqv[4*u+0] = e.x; eqv[4*u+1] = e.y; eqv[4*u+2] = e.z; eqv[4*u+3] = e.w;
      wv2[4*u+0] = -2.f * v.x; wv2[4*u+1] = -2.f * v.y;
      wv2[4*u+2] = -2.f * v.z; wv2[4*u+3] = -2.f * v.w;
      w0 += v.x + v.y + v.z + v.w;
    }
  }

  const int ktiles = (vl + 127) >> 7;
  const int kp = 2 * lane;
  for (int kt = 0; kt < ktiles; ++kt) {
    const float* tb = EkT + ((size_t)(b * 16 + kt) * 64) * 128 + kp;
    float s0 = w0, s1 = w0;
    #pragma unroll
    for (int h = 0; h < 64; ++h) {
      float2 ek = *(const float2*)(tb + (size_t)h * 128);
      float r0 = fast_rcp(fmaf(eqv[h], ek.x, 1.0f));
      float r1 = fast_rcp(fmaf(eqv[h], ek.y, 1.0f));
      s0 = fmaf(wv2[h], r0, s0);
      s1 = fmaf(wv2[h], r1, s1);
    }
    int k = kt * 128 + kp;
    if (k     >= vl) s0 = -1e9f;
    if (k + 1 >= vl) s1 = -1e9f;
    float* scf = (float*)sc4;
    *(float2*)(scf + (((k >> 2) * 4 + wave) * 4 + (k & 3))) = make_float2(s0, s1);
  }

  const int nq4 = (vl + 3) >> 2;
  float mx = -3e38f;
  for (int Q = lane; Q < nq4; Q += 64) {
    float4 f = sc4[Q * 4 + wave];
    mx = fmaxf(mx, fmaxf(fmaxf(f.x, f.y), fmaxf(f.z, f.w)));
  }
  #pragma unroll
  for (int msk = 1; msk < 64; msk <<= 1) mx = fmaxf(mx, __shfl_xor(mx, msk, 64));
  float lsum = 0.f;
  for (int Q = lane; Q < nq4; Q += 64) {
    float4 f = sc4[Q * 4 + wave];
    f.x = fast_exp2((f.x - mx) * L2E);
    f.y = fast_exp2((f.y - mx) * L2E);
    f.z = fast_exp2((f.z - mx) * L2E);
    f.w = fast_exp2((f.w - mx) * L2E);
    sc4[Q * 4 + wave] = f;
    lsum += f.x + f.y + f.z + f.w;
  }
  #pragma unroll
  for (int msk = 1; msk < 64; msk <<= 1) lsum += __shfl_xor(lsum, msk, 64);
  if (lane == 0) linvs[wave] = fast_rcp(lsum);
  __syncthreads();

  const int grp = t >> 7, v = t & 127;
  float acc[4] = {0.f, 0.f, 0.f, 0.f};
  const float* vb = values + (size_t)b * 2048 * 128 + v;
  for (int Q = grp; Q < nq4; Q += 2) {
    float4 p0 = sc4[Q * 4 + 0], p1 = sc4[Q * 4 + 1];
    float4 p2 = sc4[Q * 4 + 2], p3 = sc4[Q * 4 + 3];
    const float* vk = vb + (size_t)(Q * 4) * 128;
    float x;
    x = vk[0];
    acc[0]=fmaf(p0.x,x,acc[0]); acc[1]=fmaf(p1.x,x,acc[1]);
    acc[2]=fmaf(p2.x,x,acc[2]); acc[3]=fmaf(p3.x,x,acc[3]);
    x = vk[128];
    acc[0]=fmaf(p0.y,x,acc[0]); acc[1]=fmaf(p1.y,x,acc[1]);
    acc[2]=fmaf(p2.y,x,acc[2]); acc[3]=fmaf(p3.y,x,acc[3]);
    x = vk[256];
    acc[0]=fmaf(p0.z,x,acc[0]); acc[1]=fmaf(p1.z,x,acc[1]);
    acc[2]=fmaf(p2.z,x,acc[2]); acc[3]=fmaf(p3.z,x,acc[3]);
    x = vk[384];
    acc[0]=fmaf(p0.w,x,acc[0]); acc[1]=fmaf(p1.w,x,acc[1]);
    acc[2]=fmaf(p2.w,x,acc[2]); acc[3]=fmaf(p3.w,x,acc[3]);
  }
  if (grp == 1) {
    #pragma unroll
    for (int qq = 0; qq < 4; ++qq) pvp[v * 5 + qq] = acc[qq];
  }
  __syncthreads();
  if (grp == 0) {
    #pragma unroll
    for (int qq = 0; qq < 4; ++qq) {
      float tot = acc[qq] + pvp[v * 5 + qq];
      out[((size_t)(b * 128) + qt * 4 + qq) * 128 + v] = tot * linvs[qq];
    }
  }
}

// ---------------------------------------------------------------------------
extern "C" void kernel_launch(void* const* d_in, const int* in_sizes, int n_in,
                              void* d_out, int out_size, void* d_ws, size_t ws_size,
                              hipStream_t stream) {
  const float* queries = (const float*)d_in[0];   // [16][128][256]
  const float* keys    = (const float*)d_in[1];   // [16][2048][256]
  const float* values  = (const float*)d_in[2];   // [16][2048][128]
  const int*   vlens   = (const int*)d_in[3];     // [16]
  const float* Wq      = (const float*)d_in[4];   // [256][64]
  const float* Wk      = (const float*)d_in[5];   // [256][64]
  const float* wv      = (const float*)d_in[6];   // [64]
  float* outp = (float*)d_out;

  float* base    = (float*)d_ws;
  float* EqW     = base;                   // 262144 f  float4[b*128+q][32hp]
  float* EkP     = base + 262144;          // 2097152 f packed [b][kt][hp][k][2]
  float* tsumb   = base + 2359296;         // 32768 f   [b][kt][q]
  float* partial = base + 2392064;         // 4194304 f [b][q][kt][v]
  int*   meta    = (int*)(base + 6586368); // 64 ints
  const size_t need = (size_t)6586368 * 4 + 256;

  if (ws_size >= need) {
    hipLaunchKernelGGL(proj_qk_kernel, dim3(545), dim3(256), 0, stream,
                       queries, keys, Wq, Wk, EqW, EkP, wv, vlens, meta);
    hipLaunchKernelGGL(scorepv_kernel, dim3(768), dim3(512), 0, stream,
                       EqW, EkP, values, vlens, wv, partial, tsumb, meta);
    hipLaunchKernelGGL(reduce_kernel, dim3(1024), dim3(256), 0, stream,
                       partial, tsumb, vlens, outp);
  } else {
    hipLaunchKernelGGL((proj_kernel<0, false>), dim3(32), dim3(256), 0, stream,
                       queries, Wq, EqW, (const int*)nullptr, 128);
    hipLaunchKernelGGL((proj_kernel<1, true>), dim3(512), dim3(256), 0, stream,
                       keys, Wk, EkP, vlens, 2048);
    hipLaunchKernelGGL(attn_kernel, dim3(512), dim3(256), 0, stream,
                       EqW, EkP, values, vlens, wv, outp);
  }
}

// Round 18
// 79.445 us; speedup vs baseline: 1.0759x; 1.0759x over previous
//
#include <hip/hip_runtime.h>
#include <stddef.h>

// Additive attention: out = softmax_k(mask(sum_h wv_h * tanh(qW_h + kW_h))) @ V
// tanh(q+k) = 1 - 2/(1 + e^{2q} e^{2k})  -> precompute Eq=e^{2q}, Ek=e^{2k};
// score = W0 + sum_h wv2_h * rcp(1 + Eq_h*Ek_h); |score| <= W1 = sum|wv| ->
// p = exp2((s-W1)*L2E) in (0,1], no max pass; normalize at the end.
//
// Round-18 = Round-15 (best, 83.2us; scorepv kept byte-identical) +
// (a) proj inner loop reads klds as float4 per 4-d chunk (proj was LDS-bound:
//     4 scalar b32 reads/d -> ~20K LDS cyc/block; now ~4x fewer k-operand ops)
// (b) init merged into proj launch (block 544), one fewer kernel.

__device__ __forceinline__ float fast_rcp(float x)  { return __builtin_amdgcn_rcpf(x); }
__device__ __forceinline__ float fast_exp2(float x) { return __builtin_amdgcn_exp2f(x); }

#define C2F 2.88539008177792681f   // 2*log2(e)
#define L2E 1.44269504088896340f   // log2(e)

#if __has_builtin(__builtin_amdgcn_global_load_lds)
#define HAS_GLL 1
__device__ __forceinline__ void gload_lds16(const void* gsrc, void* ldst) {
  __builtin_amdgcn_global_load_lds(
      (const __attribute__((address_space(1))) unsigned int*)gsrc,
      (__attribute__((address_space(3))) unsigned int*)ldst, 16, 0, 0);
}
#else
#define HAS_GLL 0
#endif

// meta ints: [0]=cnt_score [1]=n_score ; [32..48]=pre_sc (prefix ceil(vl/128))
#define M_CNTS 0
#define M_NS   1
#define M_PSC  32

// ---------------------------------------------------------------------------
// Projection body: P = in[64 rows x 256] @ W[256 x 64], E = exp2(C2F*P).
// MODE 0: row-major [row][64]           (fallback queries)
// MODE 1: legacy EkT [b][kt][h][128]    (fallback keys)
// MODE 2: packed Ek  [b][kt][hp][k][2]  (main keys)
// MODE 3: packed EqW [b][q][hp]{eq0,eq1,-2wv0,-2wv1} float4 (main queries)
// Inner loop: klds read as float4 per 4-d chunk (LDS-op count /~3).
// ---------------------------------------------------------------------------
template<int MODE>
__device__ __forceinline__
void proj_body(const float* __restrict__ inb, const float* __restrict__ W,
               float* __restrict__ out, const float* __restrict__ wv,
               int b, int r0, int rowsPerB, int t)
{
  __shared__ float4 Wlds[256 * 16];   // [d][h-quad] 64KB
  __shared__ float  klds[64 * 36];    // 9.2KB; row*36 % 4 == 0 -> f4-aligned

  const float4* W4 = (const float4*)W;
#if HAS_GLL
  {
    float4* wdst = Wlds + (t & ~63);          // wave-uniform base
    #pragma unroll
    for (int i = 0; i < 16; ++i)
      gload_lds16(W4 + t + 256 * i, wdst + 256 * i);
  }
#else
  #pragma unroll
  for (int i = 0; i < 16; ++i) Wlds[t + 256 * i] = W4[t + 256 * i];
#endif

  const int j = t >> 4;
  const int g = t & 15;

  float acc[4][4];
  #pragma unroll
  for (int m = 0; m < 4; ++m)
    acc[m][0] = acc[m][1] = acc[m][2] = acc[m][3] = 0.f;

  for (int dc = 0; dc < 8; ++dc) {
    {
      const int row = t >> 2, cs = (t & 3) * 8;
      const float* s = inb + row * 256 + dc * 32 + cs;
      float4 a0 = *(const float4*)s;
      float4 a1 = *(const float4*)(s + 4);
      float* dst = &klds[row * 36 + cs];
      *(float4*)dst       = a0;
      *(float4*)(dst + 4) = a1;
    }
    __syncthreads();
    #pragma unroll
    for (int d4 = 0; d4 < 8; ++d4) {
      float4 kv4[4];
      #pragma unroll
      for (int m = 0; m < 4; ++m)
        kv4[m] = *(const float4*)&klds[(g + 16 * m) * 36 + d4 * 4];
      #pragma unroll
      for (int dd = 0; dd < 4; ++dd) {
        float4 w4 = Wlds[(dc * 32 + d4 * 4 + dd) * 16 + j];
        #pragma unroll
        for (int m = 0; m < 4; ++m) {
          float kv = ((const float*)&kv4[m])[dd];   // static index (unrolled)
          acc[m][0] = fmaf(kv, w4.x, acc[m][0]);
          acc[m][1] = fmaf(kv, w4.y, acc[m][1]);
          acc[m][2] = fmaf(kv, w4.z, acc[m][2]);
          acc[m][3] = fmaf(kv, w4.w, acc[m][3]);
        }
      }
    }
    __syncthreads();
  }

  if constexpr (MODE == 1) {
    #pragma unroll
    for (int m = 0; m < 4; ++m) {
      int k = r0 + g + 16 * m;
      size_t base = ((size_t)(b * 16 + (k >> 7)) * 64) * 128 + (k & 127);
      #pragma unroll
      for (int i = 0; i < 4; ++i)
        out[base + (size_t)(4 * j + i) * 128] = fast_exp2(C2F * acc[m][i]);
    }
  } else if constexpr (MODE == 2) {
    // packed: idx = tile*8192 + hp*256 + k_in*2 + hl, hp = h>>1
    #pragma unroll
    for (int m = 0; m < 4; ++m) {
      int k = r0 + g + 16 * m;
      size_t base = (size_t)(b * 16 + (k >> 7)) * 8192 + (size_t)(k & 127) * 2;
      float e0 = fast_exp2(C2F * acc[m][0]);
      float e1 = fast_exp2(C2F * acc[m][1]);
      float e2 = fast_exp2(C2F * acc[m][2]);
      float e3 = fast_exp2(C2F * acc[m][3]);
      *(float2*)&out[base + (size_t)(2 * j) * 256]     = make_float2(e0, e1);
      *(float2*)&out[base + (size_t)(2 * j + 1) * 256] = make_float2(e2, e3);
    }
  } else if constexpr (MODE == 3) {
    // EqW float4 [b*128+row][32hp]: {eq(2hp), eq(2hp+1), -2wv(2hp), -2wv(2hp+1)}
    float4 wq = ((const float4*)wv)[j];   // epilogue-only load
    #pragma unroll
    for (int m = 0; m < 4; ++m) {
      int row = r0 + g + 16 * m;
      float e0 = fast_exp2(C2F * acc[m][0]);
      float e1 = fast_exp2(C2F * acc[m][1]);
      float e2 = fast_exp2(C2F * acc[m][2]);
      float e3 = fast_exp2(C2F * acc[m][3]);
      float4* dst = (float4*)out + ((size_t)(b * 128 + row)) * 32;
      dst[2 * j]     = make_float4(e0, e1, -2.f * wq.x, -2.f * wq.y);
      dst[2 * j + 1] = make_float4(e2, e3, -2.f * wq.z, -2.f * wq.w);
    }
  } else {
    #pragma unroll
    for (int m = 0; m < 4; ++m) {
      int row = r0 + g + 16 * m;
      float4 o;
      o.x = fast_exp2(C2F * acc[m][0]);
      o.y = fast_exp2(C2F * acc[m][1]);
      o.z = fast_exp2(C2F * acc[m][2]);
      o.w = fast_exp2(C2F * acc[m][3]);
      *(float4*)&out[((size_t)b * rowsPerB + row) * 64 + 4 * j] = o;
    }
  }
}

// Merged q+k projection + init: blocks 0..511 keys (early-exit),
// 512..543 queries, 544 = meta init (single block).
__global__ __launch_bounds__(256)
void proj_qk_kernel(const float* __restrict__ queries, const float* __restrict__ keys,
                    const float* __restrict__ Wq, const float* __restrict__ Wk,
                    float* __restrict__ EqW, float* __restrict__ EkP,
                    const float* __restrict__ wv, const int* __restrict__ vlens,
                    int* __restrict__ meta)
{
  const int blk = blockIdx.x;
  if (blk == 544) {
    if (threadIdx.x == 0) {
      int as = 0;
      meta[M_PSC] = 0;
      for (int b = 0; b < 16; ++b) {
        as += (vlens[b] + 127) >> 7;
        meta[M_PSC + 1 + b] = as;
      }
      meta[M_NS]   = as * 8;     // 8 q-tiles (16 q) per active (b,kt)
      meta[M_CNTS] = 0;
    }
    return;
  }
  if (blk >= 512) {
    const int idx = blk - 512;
    const int b = idx & 15, rt = idx >> 4, r0 = rt * 64;
    proj_body<3>(queries + ((size_t)b * 128 + r0) * 256, Wq, EqW, wv, b, r0, 128,
                 threadIdx.x);
  } else {
    const int b = blk & 15, rt = blk >> 4, r0 = rt * 64;
    if (r0 >= vlens[b]) return;
    proj_body<2>(keys + ((size_t)b * 2048 + r0) * 256, Wk, EkP, wv, b, r0, 2048,
                 threadIdx.x);
  }
}

// Fallback projections (legacy layouts)
template<int MODE, bool CHECK>
__global__ __launch_bounds__(256)
void proj_kernel(const float* __restrict__ in, const float* __restrict__ W,
                 float* __restrict__ out, const int* __restrict__ vlens,
                 int rowsPerB)
{
  const int t  = threadIdx.x;
  const int b  = blockIdx.x & 15;
  const int rt = blockIdx.x >> 4;
  const int r0 = rt * 64;
  if constexpr (CHECK) {
    if (r0 >= vlens[b]) return;
  }
  proj_body<MODE>(in + ((size_t)b * rowsPerB + r0) * 256, W, out,
                  (const float*)nullptr, b, r0, rowsPerB, t);
}

// ---------------------------------------------------------------------------
// Persistent fused scores + exp + PV partial (R15, byte-identical).
// 512 thr = 8 waves; wave owns 2 q. Unit u: w=u>>3 -> (b,kt); qq=u&7.
// ---------------------------------------------------------------------------
__global__ __launch_bounds__(512, 6)
void scorepv_kernel(const float* __restrict__ EqW, const float* __restrict__ EkP,
                    const float* __restrict__ values, const int* __restrict__ vlens,
                    const float* __restrict__ wv,
                    float* __restrict__ partial, float* __restrict__ tsum,
                    int* __restrict__ meta)
{
  __shared__ float ek_lds[8192];       // 32KB packed ek [hp][k][2]; red later
  __shared__ float eqw_lds[2048];      // 8KB: 16q x 32hp float4
  __shared__ float p_lds[128 * 20];    // 10KB: p [128k][20pad] (dedicated)
  __shared__ int sh_u, sh_pre[17];

  const int t = threadIdx.x;
  if (t < 17) sh_pre[t] = meta[M_PSC + t];
  const int nunits = meta[M_NS];

  // W1 = sum|wv|, W0 = sum wv (once; outside hot loop)
  float W1 = 0.f, w0 = 0.f;
  #pragma unroll
  for (int u = 0; u < 16; ++u) {
    float4 v = ((const float4*)wv)[u];
    w0 += v.x + v.y + v.z + v.w;
    W1 += fabsf(v.x) + fabsf(v.y) + fabsf(v.z) + fabsf(v.w);
  }

  const int wave_u = __builtin_amdgcn_readfirstlane(t >> 6);  // 0..7 uniform
  const int lane   = t & 63;
  const int kp     = lane * 2;
  const int q0l    = wave_u * 2;

  for (;;) {
    __syncthreads();                 // prev unit's LDS readers done
    if (t == 0) sh_u = atomicAdd(&meta[M_CNTS], 1);
    __syncthreads();
    const int u = sh_u;
    if (u >= nunits) break;

    const int w  = u >> 3;
    const int qq = u & 7;
    int b = 0;
    while (w >= sh_pre[1 + b]) ++b;
    const int kt = w - sh_pre[b];
    const int vl = vlens[b];

    // stage ek (32KB) + eqw (8KB), both lane-contiguous -> global_load_lds
    {
      const float4* src  = (const float4*)(EkP + (size_t)(b * 16 + kt) * 8192);
      const float4* qsrc = (const float4*)EqW + ((size_t)(b * 128 + qq * 16)) * 32;
#if HAS_GLL
      float4* dstw = (float4*)ek_lds + (t & ~63);     // wave-uniform base
      #pragma unroll
      for (int i = 0; i < 4; ++i)
        gload_lds16(src + t + 512 * i, dstw + 512 * i);
      gload_lds16(qsrc + t, (float4*)eqw_lds + (t & ~63));
#else
      float4* dst = (float4*)ek_lds;
      #pragma unroll
      for (int i = 0; i < 4; ++i) dst[t + 512 * i] = src[t + 512 * i];
      ((float4*)eqw_lds)[t] = qsrc[t];
#endif
    }
    __syncthreads();                 // staging complete (vmcnt drained)

    float s[2][2] = {{w0, w0}, {w0, w0}};
    const float4* ek4 = (const float4*)ek_lds;
    const float4* eqw = (const float4*)eqw_lds;
    #pragma unroll 8
    for (int hp = 0; hp < 32; ++hp) {
      float4 e = ek4[hp * 64 + lane];          // (k,h0)(k,h1)(k+1,h0)(k+1,h1)
      #pragma unroll
      for (int q = 0; q < 2; ++q) {
        float4 ew = eqw[(q0l + q) * 32 + hp];  // {eq0,eq1,wa,wb} broadcast
        { float x0 = fmaf(ew.x, e.x, 1.f), x1 = fmaf(ew.y, e.y, 1.f);
          float y = fast_rcp(x0 * x1);
          float a = ew.w * x0; a = fmaf(ew.z, x1, a);
          s[q][0] = fmaf(a, y, s[q][0]); }
        { float x0 = fmaf(ew.x, e.z, 1.f), x1 = fmaf(ew.y, e.w, 1.f);
          float y = fast_rcp(x0 * x1);
          float a = ew.w * x0; a = fmaf(ew.z, x1, a);
          s[q][1] = fmaf(a, y, s[q][1]); }
      }
    }

    // p = exp2((s - W1)*L2E) in (0,1]; masked -> 0 (select, garbage-safe)
    const int kbase = kt * 128 + kp;
    float p[2][2];
    #pragma unroll
    for (int q = 0; q < 2; ++q) {
      p[q][0] = (kbase     < vl) ? fast_exp2((s[q][0] - W1) * L2E) : 0.f;
      p[q][1] = (kbase + 1 < vl) ? fast_exp2((s[q][1] - W1) * L2E) : 0.f;
    }

    // p -> dedicated p_lds (prev readers done at loop-top barrier)
    *(float2*)&p_lds[kp * 20 + q0l]       = make_float2(p[0][0], p[1][0]);
    *(float2*)&p_lds[(kp + 1) * 20 + q0l] = make_float2(p[0][1], p[1][1]);

    // per-tile row sums (wave owns its q rows exclusively)
    const int q0g = qq * 16 + q0l;
    #pragma unroll
    for (int q = 0; q < 2; ++q) {
      float e = p[q][0] + p[q][1];
      #pragma unroll
      for (int m = 1; m < 64; m <<= 1) e += __shfl_xor(e, m, 64);
      if (lane == 0) tsum[(size_t)(b * 16 + kt) * 128 + q0g + q] = e;
    }
    __syncthreads();                 // p visible to all

    // PV: thread (kg 0..3, v); kg owns 32 k; 8-deep V-load batches;
    // p via broadcast ds_read_b128 (same-address: conflict-free)
    const int kg = t >> 7, v = t & 127;
    const int kloc = min(128, vl - kt * 128);
    const int k0 = kg * 32, k1 = min(k0 + 32, kloc);
    const int len = (k1 > k0) ? (k1 - k0) : 0;   // clamp (k1 may be < k0)
    const int nfull = len & ~7;
    const float* vb = values + ((size_t)(b * 2048 + kt * 128)) * 128 + v;
    float acc[16];
    #pragma unroll
    for (int i = 0; i < 16; ++i) acc[i] = 0.f;

    for (int kb = k0; kb < k0 + nfull; kb += 8) {
      float vv[8];
      #pragma unroll
      for (int j = 0; j < 8; ++j) vv[j] = vb[(size_t)(kb + j) * 128];
      #pragma unroll
      for (int j = 0; j < 8; ++j) {
        const float* pr = &p_lds[(kb + j) * 20];
        float4 p0 = *(const float4*)&pr[0];
        float4 p1 = *(const float4*)&pr[4];
        float4 p2 = *(const float4*)&pr[8];
        float4 p3 = *(const float4*)&pr[12];
        float vx = vv[j];
        acc[ 0]=fmaf(p0.x,vx,acc[ 0]); acc[ 1]=fmaf(p0.y,vx,acc[ 1]);
        acc[ 2]=fmaf(p0.z,vx,acc[ 2]); acc[ 3]=fmaf(p0.w,vx,acc[ 3]);
        acc[ 4]=fmaf(p1.x,vx,acc[ 4]); acc[ 5]=fmaf(p1.y,vx,acc[ 5]);
        acc[ 6]=fmaf(p1.z,vx,acc[ 6]); acc[ 7]=fmaf(p1.w,vx,acc[ 7]);
        acc[ 8]=fmaf(p2.x,vx,acc[ 8]); acc[ 9]=fmaf(p2.y,vx,acc[ 9]);
        acc[10]=fmaf(p2.z,vx,acc[10]); acc[11]=fmaf(p2.w,vx,acc[11]);
        acc[12]=fmaf(p3.x,vx,acc[12]); acc[13]=fmaf(p3.y,vx,acc[13]);
        acc[14]=fmaf(p3.z,vx,acc[14]); acc[15]=fmaf(p3.w,vx,acc[15]);
      }
    }
    for (int k = k0 + nfull; k < k1; ++k) {      // remainder (partial tiles)
      float vx = vb[(size_t)k * 128];
      const float* pr = &p_lds[k * 20];
      #pragma unroll
      for (int q = 0; q < 16; ++q) acc[q] = fmaf(pr[q], vx, acc[q]);
    }

    // 4-way reduction over kg (reuse ek region; ek reads ended pre-barrier)
    __syncthreads();                 // all p reads done
    float* red = ek_lds;
    if (kg > 0) {
      #pragma unroll
      for (int q = 0; q < 16; ++q) red[(kg - 1) * 2048 + q * 128 + v] = acc[q];
    }
    __syncthreads();
    if (kg == 0) {
      #pragma unroll
      for (int q = 0; q < 16; ++q) {
        float tot = acc[q] + red[q * 128 + v] + red[2048 + q * 128 + v]
                  + red[4096 + q * 128 + v];
        partial[(((size_t)(b * 128 + qq * 16 + q)) * 16 + kt) * 128 + v] = tot;
      }
    }
  }
}

// ---------------------------------------------------------------------------
// Reduce: out[b][q][v] = sum_kt partial / sum_kt tsum. Block = (b, 2-q), 256 thr.
// ---------------------------------------------------------------------------
__global__ __launch_bounds__(256)
void reduce_kernel(const float* __restrict__ partial, const float* __restrict__ tsum,
                   const int* __restrict__ vlens, float* __restrict__ out)
{
  const int blk = blockIdx.x;          // b*64 + qp
  const int b   = blk >> 6;
  const int q   = (blk & 63) * 2 + (threadIdx.x >> 7);
  const int v   = threadIdx.x & 127;
  const int ntk = (vlens[b] + 127) >> 7;

  float tot = 0.f;
  for (int i = 0; i < ntk; ++i)
    tot += tsum[(size_t)(b * 16 + i) * 128 + q];

  float acc = 0.f;
  const float* pp = partial + ((size_t)(b * 128 + q)) * 16 * 128 + v;
  for (int i = 0; i < ntk; ++i)
    acc += pp[(size_t)i * 128];

  out[((size_t)(b * 128 + q)) * 128 + v] = acc / tot;
}

// ---------------------------------------------------------------------------
// Fallback fused kernel (round-1, known-correct) for small ws_size.
// ---------------------------------------------------------------------------
__global__ __launch_bounds__(256)
void attn_kernel(const float* __restrict__ Eq, const float* __restrict__ EkT,
                 const float* __restrict__ values, const int* __restrict__ vlens,
                 const float* __restrict__ wv, float* __restrict__ out)
{
  const int t    = threadIdx.x;
  const int b    = blockIdx.x & 15;
  const int qt   = blockIdx.x >> 4;
  const int wave = t >> 6;
  const int lane = t & 63;

  __shared__ float4 sc4[512 * 4];
  __shared__ float  pvp[128 * 5];
  __shared__ float  linvs[4];

  const int vl = vlens[b];

  float eqv[64], wv2[64];
  float w0 = 0.f;
  {
    const float4* eq4 = (const float4*)(Eq + (size_t)(b * 128 + qt * 4 + wave) * 64);
    const float4* wv4 = (const float4*)wv;
    #pragma unroll
    for (int u = 0; u < 16; ++u) {
      float4 e = eq4[u], v = wv4[u];
      eqv[4*u+0] = e.x; eqv[4*u+1] = e.y; eqv[4*u+2] = e.z; eqv[4*u+3] = e.w;
      wv2[4*u+0] = -2.f * v.x; wv2[4*u+1] = -2.f * v.y;
      wv2[4*u+2] = -2.f * v.z; wv2[4*u+3] = -2.f * v.w;
      w0 += v.x + v.y + v.z + v.w;
    }
  }

  const int ktiles = (vl + 127) >> 7;
  const int kp = 2 * lane;
  for (int kt = 0; kt < ktiles; ++kt) {
    const float* tb = EkT + ((size_t)(b * 16 + kt) * 64) * 128 + kp;
    float s0 = w0, s1 = w0;
    #pragma unroll
    for (int h = 0; h < 64; ++h) {
      float2 ek = *(const float2*)(tb + (size_t)h * 128);
      float r0 = fast_rcp(fmaf(eqv[h], ek.x, 1.0f));
      float r1 = fast_rcp(fmaf(eqv[h], ek.y, 1.0f));
      s0 = fmaf(wv2[h], r0, s0);
      s1 = fmaf(wv2[h], r1, s1);
    }
    int k = kt * 128 + kp;
    if (k     >= vl) s0 = -1e9f;
    if (k + 1 >= vl) s1 = -1e9f;
    float* scf = (float*)sc4;
    *(float2*)(scf + (((k >> 2) * 4 + wave) * 4 + (k & 3))) = make_float2(s0, s1);
  }

  const int nq4 = (vl + 3) >> 2;
  float mx = -3e38f;
  for (int Q = lane; Q < nq4; Q += 64) {
    float4 f = sc4[Q * 4 + wave];
    mx = fmaxf(mx, fmaxf(fmaxf(f.x, f.y), fmaxf(f.z, f.w)));
  }
  #pragma unroll
  for (int msk = 1; msk < 64; msk <<= 1) mx = fmaxf(mx, __shfl_xor(mx, msk, 64));
  float lsum = 0.f;
  for (int Q = lane; Q < nq4; Q += 64) {
    float4 f = sc4[Q * 4 + wave];
    f.x = fast_exp2((f.x - mx) * L2E);
    f.y = fast_exp2((f.y - mx) * L2E);
    f.z = fast_exp2((f.z - mx) * L2E);
    f.w = fast_exp2((f.w - mx) * L2E);
    sc4[Q * 4 + wave] = f;
    lsum += f.x + f.y + f.z + f.w;
  }
  #pragma unroll
  for (int msk = 1; msk < 64; msk <<= 1) lsum += __shfl_xor(lsum, msk, 64);
  if (lane == 0) linvs[wave] = fast_rcp(lsum);
  __syncthreads();

  const int grp = t >> 7, v = t & 127;
  float acc[4] = {0.f, 0.f, 0.f, 0.f};
  const float* vb = values + (size_t)b * 2048 * 128 + v;
  for (int Q = grp; Q < nq4; Q += 2) {
    float4 p0 = sc4[Q * 4 + 0], p1 = sc4[Q * 4 + 1];
    float4 p2 = sc4[Q * 4 + 2], p3 = sc4[Q * 4 + 3];
    const float* vk = vb + (size_t)(Q * 4) * 128;
    float x;
    x = vk[0];
    acc[0]=fmaf(p0.x,x,acc[0]); acc[1]=fmaf(p1.x,x,acc[1]);
    acc[2]=fmaf(p2.x,x,acc[2]); acc[3]=fmaf(p3.x,x,acc[3]);
    x = vk[128];
    acc[0]=fmaf(p0.y,x,acc[0]); acc[1]=fmaf(p1.y,x,acc[1]);
    acc[2]=fmaf(p2.y,x,acc[2]); acc[3]=fmaf(p3.y,x,acc[3]);
    x = vk[256];
    acc[0]=fmaf(p0.z,x,acc[0]); acc[1]=fmaf(p1.z,x,acc[1]);
    acc[2]=fmaf(p2.z,x,acc[2]); acc[3]=fmaf(p3.z,x,acc[3]);
    x = vk[384];
    acc[0]=fmaf(p0.w,x,acc[0]); acc[1]=fmaf(p1.w,x,acc[1]);
    acc[2]=fmaf(p2.w,x,acc[2]); acc[3]=fmaf(p3.w,x,acc[3]);
  }
  if (grp == 1) {
    #pragma unroll
    for (int qq = 0; qq < 4; ++qq) pvp[v * 5 + qq] = acc[qq];
  }
  __syncthreads();
  if (grp == 0) {
    #pragma unroll
    for (int qq = 0; qq < 4; ++qq) {
      float tot = acc[qq] + pvp[v * 5 + qq];
      out[((size_t)(b * 128) + qt * 4 + qq) * 128 + v] = tot * linvs[qq];
    }
  }
}

// ---------------------------------------------------------------------------
extern "C" void kernel_launch(void* const* d_in, const int* in_sizes, int n_in,
                              void* d_out, int out_size, void* d_ws, size_t ws_size,
                              hipStream_t stream) {
  const float* queries = (const float*)d_in[0];   // [16][128][256]
  const float* keys    = (const float*)d_in[1];   // [16][2048][256]
  const float* values  = (const float*)d_in[2];   // [16][2048][128]
  const int*   vlens   = (const int*)d_in[3];     // [16]
  const float* Wq      = (const float*)d_in[4];   // [256][64]
  const float* Wk      = (const float*)d_in[5];   // [256][64]
  const float* wv      = (const float*)d_in[6];   // [64]
  float* outp = (float*)d_out;

  float* base    = (float*)d_ws;
  float* EqW     = base;                   // 262144 f  float4[b*128+q][32hp]
  float* EkP     = base + 262144;          // 2097152 f packed [b][kt][hp][k][2]
  float* tsumb   = base + 2359296;         // 32768 f   [b][kt][q]
  float* partial = base + 2392064;         // 4194304 f [b][q][kt][v]
  int*   meta    = (int*)(base + 6586368); // 64 ints
  const size_t need = (size_t)6586368 * 4 + 256;

  if (ws_size >= need) {
    hipLaunchKernelGGL(proj_qk_kernel, dim3(545), dim3(256), 0, stream,
                       queries, keys, Wq, Wk, EqW, EkP, wv, vlens, meta);
    hipLaunchKernelGGL(scorepv_kernel, dim3(768), dim3(512), 0, stream,
                       EqW, EkP, values, vlens, wv, partial, tsumb, meta);
    hipLaunchKernelGGL(reduce_kernel, dim3(1024), dim3(256), 0, stream,
                       partial, tsumb, vlens, outp);
  } else {
    hipLaunchKernelGGL((proj_kernel<0, false>), dim3(32), dim3(256), 0, stream,
                       queries, Wq, EqW, (const int*)nullptr, 128);
    hipLaunchKernelGGL((proj_kernel<1, true>), dim3(512), dim3(256), 0, stream,
                       keys, Wk, EkP, vlens, 2048);
    hipLaunchKernelGGL(attn_kernel, dim3(512), dim3(256), 0, stream,
                       EqW, EkP, values, vlens, wv, outp);
  }
}